// Round 3
// baseline (81.398 us; speedup 1.0000x reference)
//
#include <hip/hip_runtime.h>

#define BB 32
#define QQ 16384
#define GG 128
#define KK 32
#define NN 9
#define TT 16     // GTs per block; one phase-2 wave each
#define TH 1024   // 16 waves; 256 blocks -> 1 block/CU
#define RR (QQ / TH)  // 16 elements per thread-range
#define NW (TH / 64)  // 16 smin values per lane in phase 2
#define CAP 192   // per-GT candidate capacity (expected ~40 with tight U)
#define ACAP 96   // per-GT active-range capacity (expected ~36)
#define UF 4      // load prefetch batch

typedef unsigned long long u64;
typedef unsigned int u32;

#define INFF __uint_as_float(0x7F800000u)

// packed ascending key: (float bits of nonneg key) << 32 | idx
// lexicographic u64 compare == (value asc, index asc) == jax top_k tie rule
__device__ __forceinline__ u64 pack_asc(float key, u32 idx) {
  return (((u64)__float_as_uint(key)) << 32) | (u64)idx;
}

// EXACT reference squared distance: ((dx^2+dy^2)+dz^2)+dw^2, no contraction.
// ref d = sqrtf(this).
__device__ __forceinline__ float dist2_ref(const float4 g, const float4 p) {
#pragma clang fp contract(off)
  float dx = g.x - p.x;
  float dy = g.y - p.y;
  float dz = g.z - p.z;
  float dw = g.w - p.w;
  float s = dx * dx + dy * dy;
  s = s + dz * dz;
  s = s + dw * dw;
  return s;
}

// IoU exactly as reference (cxcywh -> xyxy, clip, same op order)
__device__ __forceinline__ float iou_ref(const float4 g, const float4 p) {
#pragma clang fp contract(off)
  float gx1 = g.x - 0.5f * g.z, gy1 = g.y - 0.5f * g.w;
  float gx2 = g.x + 0.5f * g.z, gy2 = g.y + 0.5f * g.w;
  float px1 = p.x - 0.5f * p.z, py1 = p.y - 0.5f * p.w;
  float px2 = p.x + 0.5f * p.z, py2 = p.y + 0.5f * p.w;
  float ltx = fmaxf(gx1, px1), lty = fmaxf(gy1, py1);
  float rbx = fminf(gx2, px2), rby = fminf(gy2, py2);
  float wx = fmaxf(rbx - ltx, 0.0f), wy = fmaxf(rby - lty, 0.0f);
  float inter = wx * wy;
  float aa = (gx2 - gx1) * (gy2 - gy1);
  float ab = (px2 - px1) * (py2 - py1);
  return inter / ((aa + ab) - inter);
}

// monotone bijection float -> u32 (total order preserved; no NaN inputs)
__device__ __forceinline__ u32 f2ord(float f) {
  u32 b = __float_as_uint(f);
  return (b & 0x80000000u) ? ~b : (b | 0x80000000u);
}
__device__ __forceinline__ float ord2f(u32 k) {
  return __uint_as_float((k & 0x80000000u) ? (k & 0x7FFFFFFFu) : ~k);
}

__global__ __launch_bounds__(TH, 4) void atss_kernel(
    const float4* __restrict__ pred, const float4* __restrict__ gtb,
    int* __restrict__ out) {
  __shared__ float smin[TT][TH];            // 64 KB
  __shared__ float ckey[TT][CAP];           // 12 KB
  __shared__ unsigned short cidx[TT][CAP];  // 6 KB
  __shared__ unsigned short sact[TT][ACAP]; // 3 KB
  __shared__ int kidx[TT][KK];              // 2 KB (rare fallback paths only)

  const int t = threadIdx.x;
  // XCD swizzle (round-robin block->XCD assumed): the 8 blocks of one
  // batch share an XCD; its L2 holds that batch's 256 KB pred slice.
  // f = q*64 + m*8 + x : b = 4x+q (bijective), g0 = 16m.
  const int f = blockIdx.x;
  const int b = (f & 7) * 4 + (f >> 6);
  const int g0 = ((f >> 3) & 7) * TT;

  // 16 GT boxes from block-uniform addresses -> scalar loads / SGPRs
  float4 G[TT];
#pragma unroll
  for (int gg = 0; gg < TT; ++gg) G[gg] = gtb[b * GG + g0 + gg];

  const float4* pb = pred + (size_t)b * QQ;

  // ---- pass 1: per-thread min of s = |p|^2 - 2 g.p over 16 elements ----
  // (identical to R2 -- isolating the phase-2 rewrite)
  float mn[TT];
#pragma unroll
  for (int gg = 0; gg < TT; ++gg) mn[gg] = INFF;

  float4 P[UF];
#pragma unroll
  for (int u = 0; u < UF; ++u) P[u] = pb[t + u * TH];
#pragma unroll
  for (int j = 0; j < RR; j += UF) {
    float4 C[UF];
#pragma unroll
    for (int u = 0; u < UF; ++u) C[u] = P[u];
    if (j + UF < RR) {
#pragma unroll
      for (int u = 0; u < UF; ++u) P[u] = pb[t + (j + UF + u) * TH];
    }
#pragma unroll
    for (int u = 0; u < UF; ++u) {
      float4 p = C[u];
      float pp = fmaf(p.x, p.x, fmaf(p.y, p.y, fmaf(p.z, p.z, p.w * p.w)));
      float qx = p.x + p.x, qy = p.y + p.y, qz = p.z + p.z, qw = p.w + p.w;
#pragma unroll
      for (int gg = 0; gg < TT; ++gg) {
        float acc = fmaf(-G[gg].x, qx, pp);
        acc = fmaf(-G[gg].y, qy, acc);
        acc = fmaf(-G[gg].z, qz, acc);
        acc = fmaf(-G[gg].w, qw, acc);
        mn[gg] = fminf(mn[gg], acc);
      }
    }
  }
#pragma unroll
  for (int gg = 0; gg < TT; ++gg) smin[gg][t] = mn[gg];

  __syncthreads();  // the ONLY block-wide barrier

  const int w = t >> 6;
  const int lane = t & 63;
  const u64 below = (lane == 0) ? 0ull : ((1ull << lane) - 1ull);

  // ================= wave w handles GT (g0 + w) alone =================
  const float4 gt = gtb[b * GG + g0 + w];  // wave-uniform reload

  // ---- load this GT's 1024 thread-mins; lane owns threads {lane + 64k}
  float V[NW];
#pragma unroll
  for (int k = 0; k < NW; ++k) V[k] = smin[w][lane + 64 * k];

  // ---- per-lane 2 smallest of its 16 values (branchless) ----
  float m1 = INFF, m2 = INFF;
#pragma unroll
  for (int k = 0; k < NW; ++k) {
    float v = V[k];
    float nm1 = fminf(m1, v);
    m2 = fminf(m2, fmaxf(m1, v));
    m1 = nm1;
  }

  // ---- U = EXACT 32nd smallest of the 128 kept values (2 per lane) ----
  // Ballot radix-select (kept from R2). Bound argument unchanged: the 32
  // kept values <= U are 32 DISTINCT threads' range-mins -> >= 32 distinct
  // elements have approx s <= U.
  u32 k1 = f2ord(m1), k2 = f2ord(m2);
  u32 pref = 0;
#pragma unroll
  for (int bit = 31; bit >= 0; --bit) {
    u32 tr = pref | (1u << bit);
    int c = __popcll(__ballot(k1 < tr)) + __popcll(__ballot(k2 < tr));
    if (c < 32) pref = tr;
  }
  float Us = ord2f(pref);  // wave-uniform

  float gg2 = fmaf(gt.x, gt.x,
              fmaf(gt.y, gt.y, fmaf(gt.z, gt.z, gt.w * gt.w)));
  // Inflation covers fma-form vs ref-form rounding and sqrt-collapse ties
  // (margins proven in R5-R8; 10x+ headroom retained).
  const float sUs = Us + fabsf(Us) * 2e-5f + 4e-6f;          // s-space test
  const float T = fmaxf(Us + gg2, 0.0f) * 1.00002f + 4e-6f;  // d2-space test

  // ---- compact active ranges via ballot (no LDS atomics) ----
  int na = 0;
#pragma unroll
  for (int k = 0; k < NW; ++k) {
    bool c = V[k] <= sUs;
    u64 mask = __ballot(c);
    if (c) {
      int pos = na + __popcll(mask & below);
      if (pos < ACAP) sact[w][pos] = (unsigned short)(lane + 64 * k);
    }
    na += __popcll(mask);  // wave-uniform
  }

  // ---- exact-d2 collection; ballot-compacted, 4-slot pipelined ----
  int nCand = 0;
  if (na <= ACAP) {
    // item (entry e, element) with e = lane/16 + 4s + 16*trip and FIXED
    // per-lane element offset (lane&15)*TH. Each entry covered by the 16
    // lanes sharing lane/16, one element each. sact-read + scattered VMEM
    // for trip t+1 fly while trip t is processed.
    const int eo = (lane & 15) * TH;
    const int e0 = lane >> 4;
    const int trips = (na + 15) >> 4;  // uniform; na >= 2 -> trips >= 1

#define ISSUE(ENT, VV, II, PP)                        \
  {                                                   \
    int ent_ = (ENT);                                 \
    VV = ent_ < na;                                   \
    int ecl_ = VV ? ent_ : 0;                         \
    II = (int)sact[w][ecl_] + eo;                     \
    PP = pb[II];                                      \
  }
#define PROCESS(VV, II, PP)                           \
  {                                                   \
    float d2_ = dist2_ref(gt, PP);                    \
    bool acc_ = VV && (d2_ <= T);                     \
    u64 mask_ = __ballot(acc_);                       \
    if (acc_) {                                       \
      int pos_ = nCand + __popcll(mask_ & below);     \
      if (pos_ < CAP) {                               \
        ckey[w][pos_] = d2_;                          \
        cidx[w][pos_] = (unsigned short)II;           \
      }                                               \
    }                                                 \
    nCand += __popcll(mask_);                         \
  }

    bool va, vb, vc, vd;
    int ia, ib, ic, id;
    float4 pa, pbx, pc, pd;
    ISSUE(e0, va, ia, pa);
    ISSUE(e0 + 4, vb, ib, pbx);
    ISSUE(e0 + 8, vc, ic, pc);
    ISSUE(e0 + 12, vd, id, pd);
    for (int tr = 0; tr < trips; ++tr) {
      int en = e0 + 16 * (tr + 1);
      bool nva, nvb, nvc, nvd;
      int nia, nib, nic, nid;
      float4 npa, npb, npc, npd;
      ISSUE(en, nva, nia, npa);
      ISSUE(en + 4, nvb, nib, npb);
      ISSUE(en + 8, nvc, nic, npc);
      ISSUE(en + 12, nvd, nid, npd);
      PROCESS(va, ia, pa);
      PROCESS(vb, ib, pbx);
      PROCESS(vc, ic, pc);
      PROCESS(vd, id, pd);
      va = nva; ia = nia; pa = npa;
      vb = nvb; ib = nib; pbx = npb;
      vc = nvc; ic = nic; pc = npc;
      vd = nvd; id = nid; pd = npd;
    }
#undef ISSUE
#undef PROCESS
  } else {
    // pathological: dense wave rescan of all ranges (ballot-compacted)
    for (int rr = 0; rr < NW; ++rr) {
      int r = lane + 64 * rr;
      for (int j = 0; j < RR; ++j) {
        int i = r + j * TH;
        float d2 = dist2_ref(gt, pb[i]);
        bool acc = d2 <= T;
        u64 mask = __ballot(acc);
        if (acc) {
          int pos = nCand + __popcll(mask & below);
          if (pos < CAP) {
            ckey[w][pos] = d2;
            cidx[w][pos] = (unsigned short)i;
          }
        }
        nCand += __popcll(mask);
      }
    }
  }
  const int n = nCand;  // wave-uniform; >= 32 guaranteed by the bound

  // ---- select top-32 by (d, idx) ascending; d = sqrtf(d2) (IEEE == jnp)
  int selIdx = 0;  // lane ℓ<32 ends holding pred idx of K-position ℓ
  if (n <= 64) {
    // fast path (~100%): in-register rank select. Keys unique (idx
    // embedded). rank = #{keys < mine} via uniform-index shfl broadcasts
    // (independent ops -> pipelined, no dependent DS chain), then ONE
    // ds_permute pushes idx to lane==rank. Lanes >= n all collide at
    // lane n >= 32 -- never consumed.
    bool valid = lane < n;
    float myd = valid ? sqrtf(ckey[w][lane]) : 0.0f;
    u32 myi = valid ? (u32)cidx[w][lane] : 0u;
    u64 mk = valid ? pack_asc(myd, myi) : ~0ull;
    int rank = 0;
    for (int i = 0; i < n; ++i) {  // n uniform
      u64 ki = __shfl(mk, i, 64);
      rank += (ki < mk) ? 1 : 0;
    }
    selIdx = __builtin_amdgcn_ds_permute(rank << 2, (int)myi);
  } else if (n <= CAP) {
    // 64 < n <= CAP: 32 rounds of wave-wide argmin extraction (rare)
    volatile float* vk = ckey[w];
    for (int sel = 0; sel < KK; ++sel) {
      u64 lm = ~0ull;
      int ls = -1;
      for (int s = lane; s < n; s += 64) {
        float d = sqrtf(vk[s]);  // sqrtf(inf)=inf for consumed slots
        u64 pk = pack_asc(d, (u32)cidx[w][s]);
        if (pk < lm) {
          lm = pk;
          ls = s;
        }
      }
      u64 ww = lm;
#pragma unroll
      for (int j = 32; j > 0; j >>= 1) {
        u64 o = __shfl_xor(ww, j, 64);
        ww = o < ww ? o : ww;
      }
      if (lm == ww && ls >= 0) {  // unique winner (idx unique)
        vk[ls] = INFF;            // mark used
        kidx[w][sel] = (int)(ww & 0xFFFFFFFFull);
      }
    }
    selIdx = kidx[w][lane & 31];  // same-wave DS ordering
  } else {
    // pathological-only exact serial fallback
    if (lane == 0) {
      u64 best[KK];
      for (int l = 0; l < KK; ++l) best[l] = ~0ull;
      for (int i = 0; i < QQ; ++i) {
        float d = sqrtf(dist2_ref(gt, pb[i]));
        u64 pk = pack_asc(d, (u32)i);
        if (pk < best[KK - 1]) {
          int pos = KK - 1;
          while (pos > 0 && best[pos - 1] > pk) {
            best[pos] = best[pos - 1];
            --pos;
          }
          best[pos] = pk;
        }
      }
      for (int l = 0; l < KK; ++l) kidx[w][l] = (int)(best[l] & 0xFFFFFFFFull);
    }
    selIdx = kidx[w][lane & 31];  // same-wave DS ordering
  }

  // ---- IoU of the 32 candidates, top-9 by (iou desc, K-position asc) ----
  // lane ℓ<32 holds K-position ℓ's candidate. Rank over 32 in-register
  // keys via uniform shfl broadcasts; winners store DIRECTLY to out[rank].
  {
    float iou = 0.0f;
    u32 pi = 0;
    if (lane < KK) {
      pi = (u32)selIdx;
      iou = iou_ref(gt, pb[pi]);
    }
    // ~bits(iou) strictly decreasing in iou (iou >= 0): smaller key ==
    // higher iou; ties -> lower K-position (i < lane term).
    u32 ik = (lane < KK) ? ~__float_as_uint(iou) : 0xFFFFFFFFu;
    int r9 = 0;
    for (int i = 0; i < KK; ++i) {
      u32 ki = __shfl(ik, i, 64);
      r9 += ((ki < ik) || (ki == ik && i < lane)) ? 1 : 0;
    }
    if (lane < KK && r9 < NN) {
      int base = (b * GG + g0 + w) * NN + r9;
      out[base] = (int)pi;                // pred_idx
      out[BB * GG * NN + base] = g0 + w;  // gt_idx
    }
  }
}

extern "C" void kernel_launch(void* const* d_in, const int* in_sizes, int n_in,
                              void* d_out, int out_size, void* d_ws, size_t ws_size,
                              hipStream_t stream) {
  (void)in_sizes;
  (void)n_in;
  (void)out_size;
  (void)d_ws;
  (void)ws_size;
  const float4* pred = (const float4*)d_in[0];  // [B, Q, 4] f32
  const float4* gt = (const float4*)d_in[1];    // [B, G, 4] f32
  int* out = (int*)d_out;                       // [2 * B * G * N] int32
  atss_kernel<<<(GG / TT) * BB, TH, 0, stream>>>(pred, gt, out);
}